// Round 4
// baseline (194.022 us; speedup 1.0000x reference)
//
#include <hip/hip_runtime.h>

#define NEGV -10000.0f

typedef _Float16 f16x8 __attribute__((ext_vector_type(8)));
typedef _Float16 f16x2 __attribute__((ext_vector_type(2)));
typedef float floatx4 __attribute__((ext_vector_type(4)));

// key (0..319) -> source sequence row. keys 0..63 local to query block nblk,
// keys 64..319 are the 256 global positions {0,61,62,63}+64j.
__device__ __forceinline__ int src_row(int key, int nblk) {
    if (key < 64) return nblk * 64 + key;
    int g = key - 64;
    int p = g & 3;
    return (g >> 2) * 64 + (p ? (60 + p) : 0);
}

__global__ __launch_bounds__(256, 4)
void sparse_attn_kernel(const float* __restrict__ Q, const float* __restrict__ K,
                        const float* __restrict__ V, const float* __restrict__ M,
                        float* __restrict__ O)
{
    // XCD swizzle: 4 whole heads per XCD so the head's global K/V rows stay in L2.
    const int x    = blockIdx.x;
    const int bh   = (x & 7) * 4 + ((x >> 3) >> 6);   // 0..31
    const int nblk = (x >> 3) & 63;                   // query block in head
    const int b    = bh >> 4;

    const size_t hoff = (size_t)bh * (4096 * 64);
    const float* Qh = Q + hoff;
    const float* Kh = K + hoff;
    const float* Vh = V + hoff;
    float*       Oh = O + hoff;
    const float* Mb = M + (size_t)b * 4096;

    // 40960 B -> 4 blocks/CU. K image: 40 slabs x 1024 B (linear groups).
    // After QK: P frags [0,10240), VT frags [10240,20480), groups swizzled by
    // sg(g) = g ^ (g>>2) (bijective; spreads write banks, reads stay 1xb128/lane).
    __shared__ _Float16 smem[20480];
    _Float16* Pbase  = smem;
    _Float16* VTbase = smem + 10240;

    const int tid  = threadIdx.x;
    const int lane = tid & 63;
    const int wv   = tid >> 6;          // wave -> query rows wv*16..+15
    const int m    = lane & 15;
    const int quad = lane >> 4;
    const int sgl  = lane ^ (lane >> 2);               // swizzled read group
    const int cg   = lane & 15;                        // V col granule (4 floats)
    // V row-pair base: fold cg>>2 in so qv varies within a wave (bank spread)
    const int ppb  = ((wv << 2) + (lane >> 4) + ((cg >> 2) << 2)) & 15;

    // ---- mask: 5 values per lane; broadcast at acc-init via shuffle ----
    float mv[5];
    #pragma unroll
    for (int s = 0; s < 5; ++s)
        mv[s] = (Mb[src_row(s * 64 + lane, nblk)] == 0.0f) ? NEGV : 0.0f;

    // ---- Q fragments direct from global (fp16) ----
    const int qrow = nblk * 64 + wv * 16 + m;
    f16x8 qf[2];
    #pragma unroll
    for (int c = 0; c < 2; ++c) {
        const float* src = Qh + (size_t)qrow * 64 + c * 32 + quad * 8;
        float4 f0 = *(const float4*)src;
        float4 f1 = *(const float4*)(src + 4);
        qf[c][0] = (_Float16)f0.x; qf[c][1] = (_Float16)f0.y;
        qf[c][2] = (_Float16)f0.z; qf[c][3] = (_Float16)f0.w;
        qf[c][4] = (_Float16)f1.x; qf[c][5] = (_Float16)f1.y;
        qf[c][6] = (_Float16)f1.z; qf[c][7] = (_Float16)f1.w;
    }

    // ---- stage K directly in B-fragment layout (linear groups, b128 writes) ----
    #pragma unroll
    for (int it = 0; it < 10; ++it) {
        int S    = it * 256 + tid;                       // 16B slot id, 0..2559
        int row  = ((S >> 7) * 16) + (S & 15);           // t*16 + n
        int col0 = ((S >> 6) & 1) * 32 + ((S & 63) >> 4) * 8;
        const float* src = Kh + (size_t)src_row(row, nblk) * 64 + col0;
        float4 f0 = *(const float4*)src;
        float4 f1 = *(const float4*)(src + 4);
        f16x8 o;
        o[0] = (_Float16)f0.x; o[1] = (_Float16)f0.y;
        o[2] = (_Float16)f0.z; o[3] = (_Float16)f0.w;
        o[4] = (_Float16)f1.x; o[5] = (_Float16)f1.y;
        o[6] = (_Float16)f1.z; o[7] = (_Float16)f1.w;
        *(f16x8*)(&smem[S * 8]) = o;
    }

    __syncthreads();   // B1: K image complete

    // ---- QK^T: mask folded into accumulator init; 40 MFMA ----
    floatx4 acc[20];
    #pragma unroll
    for (int t = 0; t < 20; ++t) {
        float ma = __shfl(mv[t >> 2], (t & 3) * 16 + m, 64);
        acc[t][0] = ma; acc[t][1] = ma; acc[t][2] = ma; acc[t][3] = ma;
    }
    #pragma unroll
    for (int t = 0; t < 20; ++t) {
        #pragma unroll
        for (int c = 0; c < 2; ++c) {
            f16x8 kf = *(const f16x8*)(&smem[(t * 2 + c) * 512 + lane * 8]);
            acc[t] = __builtin_amdgcn_mfma_f32_16x16x32_f16(qf[c], kf, acc[t], 0, 0, 0);
        }
    }

    // ---- V chunk 0 loads (packed immediately; latency hides under softmax) ----
    f16x2 vpk[20];
    #pragma unroll
    for (int s = 0; s < 5; ++s) {
        int rl = 2 * (s * 16 + ppb);                     // chunk-local even row
        float4 f0 = *(const float4*)(Vh + (size_t)src_row(rl,     nblk) * 64 + cg * 4);
        float4 f1 = *(const float4*)(Vh + (size_t)src_row(rl + 1, nblk) * 64 + cg * 4);
        vpk[s*4+0][0] = (_Float16)f0.x; vpk[s*4+0][1] = (_Float16)f1.x;
        vpk[s*4+1][0] = (_Float16)f0.y; vpk[s*4+1][1] = (_Float16)f1.y;
        vpk[s*4+2][0] = (_Float16)f0.z; vpk[s*4+2][1] = (_Float16)f1.z;
        vpk[s*4+3][0] = (_Float16)f0.w; vpk[s*4+3][1] = (_Float16)f1.w;
    }

    // ---- softmax over 320 keys (rows quad*4+r, cols t*16+m) ----
    float rmax[4] = {-3e38f, -3e38f, -3e38f, -3e38f};
    #pragma unroll
    for (int t = 0; t < 20; ++t)
        #pragma unroll
        for (int r = 0; r < 4; ++r)
            rmax[r] = fmaxf(rmax[r], acc[t][r]);
    #pragma unroll
    for (int off = 8; off >= 1; off >>= 1)
        #pragma unroll
        for (int r = 0; r < 4; ++r)
            rmax[r] = fmaxf(rmax[r], __shfl_xor(rmax[r], off, 64));
    float rsum[4] = {0.f, 0.f, 0.f, 0.f};
    #pragma unroll
    for (int t = 0; t < 20; ++t)
        #pragma unroll
        for (int r = 0; r < 4; ++r) {
            float e = __expf(acc[t][r] - rmax[r]);
            acc[t][r] = e;                 // unnormalized; 1/sum at epilogue
            rsum[r] += e;
        }
    #pragma unroll
    for (int off = 8; off >= 1; off >>= 1)
        #pragma unroll
        for (int r = 0; r < 4; ++r)
            rsum[r] += __shfl_xor(rsum[r], off, 64);
    float rinv[4];
    #pragma unroll
    for (int r = 0; r < 4; ++r) rinv[r] = 1.0f / rsum[r];

    __syncthreads();   // B2: all QK reads of K image done

    // ---- chunk 0: P frags (keys 0..159), group-swizzled ----
    #pragma unroll
    for (int tp = 0; tp < 10; ++tp) {
        int slab = wv * 5 + (tp >> 1);
        int gb   = ((tp & 1) * 2 + (m >> 3)) * 16 + quad * 4;
        #pragma unroll
        for (int r = 0; r < 4; ++r) {
            int g  = gb + r;
            int sg = g ^ (g >> 2);
            Pbase[slab * 512 + sg * 8 + (m & 7)] = (_Float16)acc[tp][r];
        }
    }
    // ---- chunk 0: VT frags from vpk, group-swizzled ----
    #pragma unroll
    for (int s = 0; s < 5; ++s) {
        int rl   = 2 * (s * 16 + ppb);
        int slab = (cg >> 2) * 5 + (rl >> 5);
        int gq   = ((rl & 31) >> 3) * 16;
        int j0   = rl & 7;
        #pragma unroll
        for (int e = 0; e < 4; ++e) {
            int g  = gq + (cg & 3) * 4 + e;
            int sg = g ^ (g >> 2);
            *(f16x2*)(&VTbase[slab * 512 + sg * 8 + j0]) = vpk[s * 4 + e];
        }
    }
    // ---- issue V chunk-1 raw loads; latency hides under PV0 ----
    float4 vr0[5], vr1[5];
    #pragma unroll
    for (int s = 0; s < 5; ++s) {
        int key = 160 + 2 * (s * 16 + ppb);
        vr0[s] = *(const float4*)(Vh + (size_t)src_row(key,     nblk) * 64 + cg * 4);
        vr1[s] = *(const float4*)(Vh + (size_t)src_row(key + 1, nblk) * 64 + cg * 4);
    }

    __syncthreads();   // B3: P0/VT0 image complete

    floatx4 oacc[4] = {};
    #pragma unroll
    for (int kc = 0; kc < 5; ++kc) {
        f16x8 pf = *(const f16x8*)(&Pbase[(wv * 5 + kc) * 512 + sgl * 8]);
        #pragma unroll
        for (int t = 0; t < 4; ++t) {
            f16x8 vf = *(const f16x8*)(&VTbase[(t * 5 + kc) * 512 + sgl * 8]);
            oacc[t] = __builtin_amdgcn_mfma_f32_16x16x32_f16(pf, vf, oacc[t], 0, 0, 0);
        }
    }

    __syncthreads();   // B4: PV0 reads done

    // ---- chunk 1: P frags (keys 160..319) ----
    #pragma unroll
    for (int tp = 0; tp < 10; ++tp) {
        int slab = wv * 5 + (tp >> 1);
        int gb   = ((tp & 1) * 2 + (m >> 3)) * 16 + quad * 4;
        #pragma unroll
        for (int r = 0; r < 4; ++r) {
            int g  = gb + r;
            int sg = g ^ (g >> 2);
            Pbase[slab * 512 + sg * 8 + (m & 7)] = (_Float16)acc[10 + tp][r];
        }
    }
    // ---- chunk 1: VT frags (pack vr now) ----
    #pragma unroll
    for (int s = 0; s < 5; ++s) {
        int rl   = 2 * (s * 16 + ppb);                   // chunk-local
        int slab = (cg >> 2) * 5 + (rl >> 5);
        int gq   = ((rl & 31) >> 3) * 16;
        int j0   = rl & 7;
        f16x2 pk[4];
        pk[0][0] = (_Float16)vr0[s].x; pk[0][1] = (_Float16)vr1[s].x;
        pk[1][0] = (_Float16)vr0[s].y; pk[1][1] = (_Float16)vr1[s].y;
        pk[2][0] = (_Float16)vr0[s].z; pk[2][1] = (_Float16)vr1[s].z;
        pk[3][0] = (_Float16)vr0[s].w; pk[3][1] = (_Float16)vr1[s].w;
        #pragma unroll
        for (int e = 0; e < 4; ++e) {
            int g  = gq + (cg & 3) * 4 + e;
            int sg = g ^ (g >> 2);
            *(f16x2*)(&VTbase[slab * 512 + sg * 8 + j0]) = pk[e];
        }
    }

    __syncthreads();   // B5: P1/VT1 image complete

    #pragma unroll
    for (int kc = 0; kc < 5; ++kc) {
        f16x8 pf = *(const f16x8*)(&Pbase[(wv * 5 + kc) * 512 + sgl * 8]);
        #pragma unroll
        for (int t = 0; t < 4; ++t) {
            f16x8 vf = *(const f16x8*)(&VTbase[(t * 5 + kc) * 512 + sgl * 8]);
            oacc[t] = __builtin_amdgcn_mfma_f32_16x16x32_f16(pf, vf, oacc[t], 0, 0, 0);
        }
    }

    // ---- epilogue: apply 1/rowsum, store fp32 ----
    #pragma unroll
    for (int t = 0; t < 4; ++t)
        #pragma unroll
        for (int r = 0; r < 4; ++r)
            Oh[(size_t)(nblk * 64 + wv * 16 + quad * 4 + r) * 64 + t * 16 + m] =
                oacc[t][r] * rinv[r];
}

extern "C" void kernel_launch(void* const* d_in, const int* in_sizes, int n_in,
                              void* d_out, int out_size, void* d_ws, size_t ws_size,
                              hipStream_t stream) {
    const float* q    = (const float*)d_in[0];
    const float* k    = (const float*)d_in[1];
    const float* v    = (const float*)d_in[2];
    const float* mask = (const float*)d_in[3];
    float* out = (float*)d_out;
    (void)in_sizes; (void)n_in; (void)out_size; (void)d_ws; (void)ws_size;
    sparse_attn_kernel<<<2 * 16 * 64, 256, 0, stream>>>(q, k, v, mask, out);
}

// Round 5
// 160.677 us; speedup vs baseline: 1.2075x; 1.2075x over previous
//
#include <hip/hip_runtime.h>

#define NEGV -10000.0f

typedef _Float16 f16x8 __attribute__((ext_vector_type(8)));
typedef _Float16 f16x2 __attribute__((ext_vector_type(2)));
typedef float floatx4 __attribute__((ext_vector_type(4)));

// key (0..319) -> source sequence row. keys 0..63 local to query block nblk,
// keys 64..319 are the 256 global positions {0,61,62,63}+64j.
__device__ __forceinline__ int src_row(int key, int nblk) {
    if (key < 64) return nblk * 64 + key;
    int g = key - 64;
    int p = g & 3;
    return (g >> 2) * 64 + (p ? (60 + p) : 0);
}

__global__ __launch_bounds__(256, 4)
void sparse_attn_kernel(const float* __restrict__ Q, const float* __restrict__ K,
                        const float* __restrict__ V, const float* __restrict__ M,
                        float* __restrict__ O)
{
    // XCD swizzle: 4 whole heads per XCD so the head's global K/V rows stay in L2.
    const int x    = blockIdx.x;
    const int bh   = (x & 7) * 4 + ((x >> 3) >> 6);   // 0..31
    const int nblk = (x >> 3) & 63;                   // query block in head
    const int b    = bh >> 4;

    const size_t hoff = (size_t)bh * (4096 * 64);
    const float* Qh = Q + hoff;
    const float* Kh = K + hoff;
    const float* Vh = V + hoff;
    float*       Oh = O + hoff;
    const float* Mb = M + (size_t)b * 4096;

    // 40960 B -> 4 blocks/CU. K image: 40 slabs x 1024 B (linear groups).
    // After QK: P frags [0,10240), VT frags [10240,20480), groups swizzled by
    // sg(g) = g ^ (g>>2) (bijective; spreads write banks, reads stay 1xb128/lane).
    __shared__ _Float16 smem[20480];
    _Float16* Pbase  = smem;
    _Float16* VTbase = smem + 10240;

    const int tid  = threadIdx.x;
    const int lane = tid & 63;
    const int wv   = tid >> 6;          // wave -> query rows wv*16..+15
    const int m    = lane & 15;
    const int quad = lane >> 4;
    const int sgl  = lane ^ (lane >> 2);               // swizzled read group
    const int cg   = lane & 15;                        // V col granule (4 floats)
    // V row-pair base: fold cg>>2 in so qv varies within a wave (bank spread)
    const int ppb  = ((wv << 2) + (lane >> 4) + ((cg >> 2) << 2)) & 15;

    // ---- mask: 5 values per lane; broadcast at acc-init via shuffle ----
    float mv[5];
    #pragma unroll
    for (int s = 0; s < 5; ++s)
        mv[s] = (Mb[src_row(s * 64 + lane, nblk)] == 0.0f) ? NEGV : 0.0f;

    // ---- Q fragments direct from global (fp16) ----
    const int qrow = nblk * 64 + wv * 16 + m;
    f16x8 qf[2];
    #pragma unroll
    for (int c = 0; c < 2; ++c) {
        const float* src = Qh + (size_t)qrow * 64 + c * 32 + quad * 8;
        float4 f0 = *(const float4*)src;
        float4 f1 = *(const float4*)(src + 4);
        qf[c][0] = (_Float16)f0.x; qf[c][1] = (_Float16)f0.y;
        qf[c][2] = (_Float16)f0.z; qf[c][3] = (_Float16)f0.w;
        qf[c][4] = (_Float16)f1.x; qf[c][5] = (_Float16)f1.y;
        qf[c][6] = (_Float16)f1.z; qf[c][7] = (_Float16)f1.w;
    }

    // ---- stage K directly in B-fragment layout (linear groups, b128 writes) ----
    #pragma unroll
    for (int it = 0; it < 10; ++it) {
        int S    = it * 256 + tid;                       // 16B slot id, 0..2559
        int row  = ((S >> 7) * 16) + (S & 15);           // t*16 + n
        int col0 = ((S >> 6) & 1) * 32 + ((S & 63) >> 4) * 8;
        const float* src = Kh + (size_t)src_row(row, nblk) * 64 + col0;
        float4 f0 = *(const float4*)src;
        float4 f1 = *(const float4*)(src + 4);
        f16x8 o;
        o[0] = (_Float16)f0.x; o[1] = (_Float16)f0.y;
        o[2] = (_Float16)f0.z; o[3] = (_Float16)f0.w;
        o[4] = (_Float16)f1.x; o[5] = (_Float16)f1.y;
        o[6] = (_Float16)f1.z; o[7] = (_Float16)f1.w;
        *(f16x8*)(&smem[S * 8]) = o;
    }

    __syncthreads();   // B1: K image complete

    // ---- QK^T: mask folded into accumulator init; 40 MFMA ----
    floatx4 acc[20];
    #pragma unroll
    for (int t = 0; t < 20; ++t) {
        float ma = __shfl(mv[t >> 2], (t & 3) * 16 + m, 64);
        acc[t][0] = ma; acc[t][1] = ma; acc[t][2] = ma; acc[t][3] = ma;
    }
    #pragma unroll
    for (int t = 0; t < 20; ++t) {
        #pragma unroll
        for (int c = 0; c < 2; ++c) {
            f16x8 kf = *(const f16x8*)(&smem[(t * 2 + c) * 512 + lane * 8]);
            acc[t] = __builtin_amdgcn_mfma_f32_16x16x32_f16(qf[c], kf, acc[t], 0, 0, 0);
        }
    }

    // ---- softmax over 320 keys (rows quad*4+r, cols t*16+m) ----
    float rmax[4] = {-3e38f, -3e38f, -3e38f, -3e38f};
    #pragma unroll
    for (int t = 0; t < 20; ++t)
        #pragma unroll
        for (int r = 0; r < 4; ++r)
            rmax[r] = fmaxf(rmax[r], acc[t][r]);
    #pragma unroll
    for (int off = 8; off >= 1; off >>= 1)
        #pragma unroll
        for (int r = 0; r < 4; ++r)
            rmax[r] = fmaxf(rmax[r], __shfl_xor(rmax[r], off, 64));
    float rsum[4] = {0.f, 0.f, 0.f, 0.f};
    #pragma unroll
    for (int t = 0; t < 20; ++t)
        #pragma unroll
        for (int r = 0; r < 4; ++r) {
            float e = __expf(acc[t][r] - rmax[r]);
            acc[t][r] = e;                 // unnormalized; 1/sum at epilogue
            rsum[r] += e;
        }
    #pragma unroll
    for (int off = 8; off >= 1; off >>= 1)
        #pragma unroll
        for (int r = 0; r < 4; ++r)
            rsum[r] += __shfl_xor(rsum[r], off, 64);
    float rinv[4];
    #pragma unroll
    for (int r = 0; r < 4; ++r) rinv[r] = 1.0f / rsum[r];

    __syncthreads();   // B2: all QK reads of K image done

    // ---- chunk 0: P frags (keys 0..159), group-swizzled ----
    #pragma unroll
    for (int tp = 0; tp < 10; ++tp) {
        int slab = wv * 5 + (tp >> 1);
        int gb   = ((tp & 1) * 2 + (m >> 3)) * 16 + quad * 4;
        #pragma unroll
        for (int r = 0; r < 4; ++r) {
            int g  = gb + r;
            int sg = g ^ (g >> 2);
            Pbase[slab * 512 + sg * 8 + (m & 7)] = (_Float16)acc[tp][r];
        }
    }
    // ---- chunk 0: V load -> convert -> VT frags (no long-lived registers) ----
    #pragma unroll
    for (int s = 0; s < 5; ++s) {
        int rl = 2 * (s * 16 + ppb);                     // chunk-local even row
        float4 f0 = *(const float4*)(Vh + (size_t)src_row(rl,     nblk) * 64 + cg * 4);
        float4 f1 = *(const float4*)(Vh + (size_t)src_row(rl + 1, nblk) * 64 + cg * 4);
        int slab = (cg >> 2) * 5 + (rl >> 5);
        int gq   = ((rl & 31) >> 3) * 16;
        int j0   = rl & 7;
        f16x2 pk[4];
        pk[0][0] = (_Float16)f0.x; pk[0][1] = (_Float16)f1.x;
        pk[1][0] = (_Float16)f0.y; pk[1][1] = (_Float16)f1.y;
        pk[2][0] = (_Float16)f0.z; pk[2][1] = (_Float16)f1.z;
        pk[3][0] = (_Float16)f0.w; pk[3][1] = (_Float16)f1.w;
        #pragma unroll
        for (int e = 0; e < 4; ++e) {
            int g  = gq + (cg & 3) * 4 + e;
            int sg = g ^ (g >> 2);
            *(f16x2*)(&VTbase[slab * 512 + sg * 8 + j0]) = pk[e];
        }
    }

    __syncthreads();   // B3: P0/VT0 image complete

    floatx4 oacc[4] = {};
    #pragma unroll
    for (int kc = 0; kc < 5; ++kc) {
        f16x8 pf = *(const f16x8*)(&Pbase[(wv * 5 + kc) * 512 + sgl * 8]);
        #pragma unroll
        for (int t = 0; t < 4; ++t) {
            f16x8 vf = *(const f16x8*)(&VTbase[(t * 5 + kc) * 512 + sgl * 8]);
            oacc[t] = __builtin_amdgcn_mfma_f32_16x16x32_f16(pf, vf, oacc[t], 0, 0, 0);
        }
    }

    __syncthreads();   // B4: PV0 reads done

    // ---- chunk 1: P frags (keys 160..319) ----
    #pragma unroll
    for (int tp = 0; tp < 10; ++tp) {
        int slab = wv * 5 + (tp >> 1);
        int gb   = ((tp & 1) * 2 + (m >> 3)) * 16 + quad * 4;
        #pragma unroll
        for (int r = 0; r < 4; ++r) {
            int g  = gb + r;
            int sg = g ^ (g >> 2);
            Pbase[slab * 512 + sg * 8 + (m & 7)] = (_Float16)acc[10 + tp][r];
        }
    }
    // ---- chunk 1: V load -> convert -> VT frags ----
    #pragma unroll
    for (int s = 0; s < 5; ++s) {
        int rl  = 2 * (s * 16 + ppb);                    // chunk-local even row
        int key = 160 + rl;
        float4 f0 = *(const float4*)(Vh + (size_t)src_row(key,     nblk) * 64 + cg * 4);
        float4 f1 = *(const float4*)(Vh + (size_t)src_row(key + 1, nblk) * 64 + cg * 4);
        int slab = (cg >> 2) * 5 + (rl >> 5);
        int gq   = ((rl & 31) >> 3) * 16;
        int j0   = rl & 7;
        f16x2 pk[4];
        pk[0][0] = (_Float16)f0.x; pk[0][1] = (_Float16)f1.x;
        pk[1][0] = (_Float16)f0.y; pk[1][1] = (_Float16)f1.y;
        pk[2][0] = (_Float16)f0.z; pk[2][1] = (_Float16)f1.z;
        pk[3][0] = (_Float16)f0.w; pk[3][1] = (_Float16)f1.w;
        #pragma unroll
        for (int e = 0; e < 4; ++e) {
            int g  = gq + (cg & 3) * 4 + e;
            int sg = g ^ (g >> 2);
            *(f16x2*)(&VTbase[slab * 512 + sg * 8 + j0]) = pk[e];
        }
    }

    __syncthreads();   // B5: P1/VT1 image complete

    #pragma unroll
    for (int kc = 0; kc < 5; ++kc) {
        f16x8 pf = *(const f16x8*)(&Pbase[(wv * 5 + kc) * 512 + sgl * 8]);
        #pragma unroll
        for (int t = 0; t < 4; ++t) {
            f16x8 vf = *(const f16x8*)(&VTbase[(t * 5 + kc) * 512 + sgl * 8]);
            oacc[t] = __builtin_amdgcn_mfma_f32_16x16x32_f16(pf, vf, oacc[t], 0, 0, 0);
        }
    }

    // ---- epilogue: apply 1/rowsum, store fp32 ----
    #pragma unroll
    for (int t = 0; t < 4; ++t)
        #pragma unroll
        for (int r = 0; r < 4; ++r)
            Oh[(size_t)(nblk * 64 + wv * 16 + quad * 4 + r) * 64 + t * 16 + m] =
                oacc[t][r] * rinv[r];
}

extern "C" void kernel_launch(void* const* d_in, const int* in_sizes, int n_in,
                              void* d_out, int out_size, void* d_ws, size_t ws_size,
                              hipStream_t stream) {
    const float* q    = (const float*)d_in[0];
    const float* k    = (const float*)d_in[1];
    const float* v    = (const float*)d_in[2];
    const float* mask = (const float*)d_in[3];
    float* out = (float*)d_out;
    (void)in_sizes; (void)n_in; (void)out_size; (void)d_ws; (void)ws_size;
    sparse_attn_kernel<<<2 * 16 * 64, 256, 0, stream>>>(q, k, v, mask, out);
}